// Round 5
// baseline (134.464 us; speedup 1.0000x reference)
//
#include <hip/hip_runtime.h>

// B=64, L=256, C_IN=5, KERNEL=4, C=8. S=253 real steps padded to 256.
// Chen-chunked: 8 chunks x 32 steps. Kernel 1 computes 8 chunk signatures
// per batch (512 blocks x 8 i-waves = 4096 waves -> 4 waves/SIMD TLP,
// 32 serial iters instead of 256). Kernel 2 left-folds the 8 chunk sigs
// per batch with the Chen identity (exact: chunk sigs are grouplike).
#define L_IN    256
#define S_STEPS 253
#define CIN     5
#define CH_LEN  32
#define SIG_N   4680   // 8 + 64 + 512 + 4096

// ---- conv-augment one path row r (0..252) -> 8 floats -------------------
__device__ __forceinline__ void path_row(
    const float* __restrict__ x, int r,
    const float* __restrict__ w1, const float* __restrict__ b1,
    const float* __restrict__ w2, const float* __restrict__ b2,
    const float* __restrict__ w3, const float* __restrict__ b3,
    float o[8])
{
    float h1[8];
    #pragma unroll
    for (int q = 0; q < 8; ++q) h1[q] = b1[q];
    #pragma unroll
    for (int kk = 0; kk < 4; ++kk) {
        #pragma unroll
        for (int ci = 0; ci < CIN; ++ci) {
            float v = x[(r + kk) * CIN + ci];
            #pragma unroll
            for (int q = 0; q < 8; ++q) h1[q] = fmaf(v, w1[q * 20 + ci * 4 + kk], h1[q]);
        }
    }
    float r1v[8];
    #pragma unroll
    for (int q = 0; q < 8; ++q) r1v[q] = h1[q] > 0.f ? h1[q] : 0.f;
    float h2[8];
    #pragma unroll
    for (int q = 0; q < 8; ++q) h2[q] = b2[q];
    #pragma unroll
    for (int p = 0; p < 8; ++p) {
        #pragma unroll
        for (int q = 0; q < 8; ++q) h2[q] = fmaf(r1v[p], w2[q * 8 + p], h2[q]);
    }
    float r2v[8];
    #pragma unroll
    for (int q = 0; q < 8; ++q) r2v[q] = h2[q] > 0.f ? h2[q] : 0.f;
    float h30 = b3[0], h31 = b3[1];
    #pragma unroll
    for (int p = 0; p < 8; ++p) {
        h30 = fmaf(r2v[p], w3[p], h30);
        h31 = fmaf(r2v[p], w3[8 + p], h31);
    }
    #pragma unroll
    for (int cc = 0; cc < 5; ++cc) o[cc] = x[(r + 3) * CIN + cc];
    o[5] = (float)(r + 3) * (1.0f / 255.0f);
    o[6] = h30;
    o[7] = h31;
}

// ---- 32-step chunk scan, specialized on block-uniform i ------------------
template<int I>
__device__ __forceinline__ void chunk_scan(
    const float (* __restrict__ dxs)[8], int j, int k, int lane,
    float* __restrict__ wsig)
{
    float s1 = 0.f, s2 = 0.f, s3 = 0.f;
    float s4[8];
    #pragma unroll
    for (int l = 0; l < 8; ++l) s4[l] = 0.f;

    const float4* __restrict__ dx4 = reinterpret_cast<const float4*>(&dxs[0][0]);

    float own_p[4], bb_p[4];
    float4 r0_p[4], r1_p[4];
    #pragma unroll
    for (int u = 0; u < 4; ++u) {
        own_p[u] = dxs[u][k];
        bb_p[u]  = dxs[u][j];
        r0_p[u]  = dx4[2 * u];
        r1_p[u]  = dx4[2 * u + 1];
    }

    for (int tb = 0; tb < CH_LEN; tb += 4) {
        #pragma unroll
        for (int u = 0; u < 4; ++u) {
            const int tn = tb + u + 4;          // <= 35, zeroed slop rows
            float  own_n = dxs[tn][k];
            float  bb_n  = dxs[tn][j];
            float4 r0_n  = dx4[2 * tn];
            float4 r1_n  = dx4[2 * tn + 1];

            const float own = own_p[u];          // dx[k] == cc
            const float bb  = bb_p[u];           // dx[j]
            const float4 r0 = r0_p[u];
            const float4 r1 = r1_p[u];
            const float a =
                (I == 0) ? r0.x : (I == 1) ? r0.y : (I == 2) ? r0.z :
                (I == 3) ? r0.w : (I == 4) ? r1.x : (I == 5) ? r1.y :
                (I == 6) ? r1.z : r1.w;

            const float t2    = fmaf(a, 0.5f, s1);
            const float t3    = fmaf(s1, 0.5f, a * (1.0f / 6.0f));
            const float t4    = fmaf(s1, (1.0f / 6.0f), a * (1.0f / 24.0f));
            const float coef3 = fmaf(bb, t3, s2);
            const float uu    = fmaf(bb, t4, 0.5f * s2);
            const float coef4 = fmaf(own, uu, s3);
            s4[0] = fmaf(coef4, r0.x, s4[0]);
            s4[1] = fmaf(coef4, r0.y, s4[1]);
            s4[2] = fmaf(coef4, r0.z, s4[2]);
            s4[3] = fmaf(coef4, r0.w, s4[3]);
            s4[4] = fmaf(coef4, r1.x, s4[4]);
            s4[5] = fmaf(coef4, r1.y, s4[5]);
            s4[6] = fmaf(coef4, r1.z, s4[6]);
            s4[7] = fmaf(coef4, r1.w, s4[7]);
            s3 = fmaf(coef3, own, s3);
            s2 = fmaf(t2, bb, s2);
            s1 += a;

            own_p[u] = own_n; bb_p[u] = bb_n;
            r0_p[u] = r0_n;   r1_p[u] = r1_n;
        }
    }

    // write chunk sig slice: [s1(8) | s2(64) | s3(512) | s4(4096)]
    if (lane == 0) wsig[I] = s1;
    if (k == 0)    wsig[8 + I * 8 + j] = s2;
    wsig[72 + (I * 8 + j) * 8 + k] = s3;
    float4* o4 = reinterpret_cast<float4*>(wsig + 584 + (size_t)((I * 8 + j) * 8 + k) * 8);
    o4[0] = make_float4(s4[0], s4[1], s4[2], s4[3]);
    o4[1] = make_float4(s4[4], s4[5], s4[6], s4[7]);
}

// ---- kernel 1: per-(batch, chunk) conv + 32-step scan --------------------
__global__ __launch_bounds__(512) void chunk_sig_kernel(
    const float* __restrict__ inp,
    const float* __restrict__ w1, const float* __restrict__ b1,
    const float* __restrict__ w2, const float* __restrict__ b2,
    const float* __restrict__ w3, const float* __restrict__ b3,
    float* __restrict__ ws)
{
    const int blk = blockIdx.x;     // 0..511
    const int b   = blk >> 3;       // batch
    const int c   = blk & 7;        // chunk
    const int tid = threadIdx.x;    // 0..511

    __shared__ __align__(16) float pbuf[33][8];   // path rows 32c-1 .. 32c+31
    __shared__ __align__(16) float dxs[36][8];    // 32 steps + 4 zero slop

    const float* __restrict__ x = inp + b * (L_IN * CIN);

    if (tid < 33) {
        const int r = CH_LEN * c - 1 + tid;       // global path row
        if (r >= 0 && r <= 252) {
            float o[8];
            path_row(x, r, w1, b1, w2, b2, w3, b3, o);
            #pragma unroll
            for (int ch = 0; ch < 8; ++ch) pbuf[tid][ch] = o[ch];
        } else {
            #pragma unroll
            for (int ch = 0; ch < 8; ++ch) pbuf[tid][ch] = 0.f;
        }
    }
    if (tid >= 64 && tid < 96) {                  // zero slop rows 32..35
        dxs[32 + ((tid - 64) >> 3)][tid & 7] = 0.f;
    }
    __syncthreads();
    if (tid < CH_LEN) {
        const int tg = CH_LEN * c + tid;          // global step
        if (tg <= 252) {
            #pragma unroll
            for (int ch = 0; ch < 8; ++ch)
                dxs[tid][ch] = pbuf[tid + 1][ch] - pbuf[tid][ch];  // pbuf[0]=0 for c==0
        } else {
            #pragma unroll
            for (int ch = 0; ch < 8; ++ch) dxs[tid][ch] = 0.f;     // pad steps 253..255
        }
    }
    __syncthreads();

    const int wave = tid >> 6;      // i, wave-uniform
    const int lane = tid & 63;
    const int j    = lane >> 3;
    const int k    = lane & 7;
    float* __restrict__ wsig = ws + (size_t)(b * 8 + c) * SIG_N;
    switch (wave) {
        case 0: chunk_scan<0>(dxs, j, k, lane, wsig); break;
        case 1: chunk_scan<1>(dxs, j, k, lane, wsig); break;
        case 2: chunk_scan<2>(dxs, j, k, lane, wsig); break;
        case 3: chunk_scan<3>(dxs, j, k, lane, wsig); break;
        case 4: chunk_scan<4>(dxs, j, k, lane, wsig); break;
        case 5: chunk_scan<5>(dxs, j, k, lane, wsig); break;
        case 6: chunk_scan<6>(dxs, j, k, lane, wsig); break;
        default: chunk_scan<7>(dxs, j, k, lane, wsig); break;
    }
}

// ---- kernel 2: left-fold 8 chunk sigs per batch via Chen identity --------
// n1 = s1A+s1B; n2 += s1A_i*s1B_j; n3 += s1A_i*s2B[jk] + s2A[ij]*s1B_k;
// n4 += s1A_i*s3B[jkl] + s2A[ij]*s2B[kl] + s3A[ijk]*s1B_l.
__global__ __launch_bounds__(512) void fold_kernel(
    const float* __restrict__ ws, float* __restrict__ out)
{
    const int b    = blockIdx.x;    // 0..63
    const int tid  = threadIdx.x;
    const int i    = tid >> 6;      // wave-uniform
    const int lane = tid & 63;
    const int j    = lane >> 3;
    const int k    = lane & 7;
    const int row  = ((i * 8 + j) * 8 + k) * 8;

    __shared__ __align__(16) float lsig[8 * 592];   // s1|s2|s3 of 8 chunks (584 used/row)

    // preload all 8 chunks' s4 rows (global, coalesced) into registers
    float4 g0[8], g1[8];
    #pragma unroll
    for (int c = 0; c < 8; ++c) {
        const float* p4 = ws + (size_t)(b * 8 + c) * SIG_N + 584 + row;
        g0[c] = *reinterpret_cast<const float4*>(p4);
        g1[c] = *reinterpret_cast<const float4*>(p4 + 4);
    }
    // stage s1/s2/s3 of all 8 chunks into LDS (coalesced)
    #pragma unroll
    for (int c = 0; c < 8; ++c) {
        const float* sb = ws + (size_t)(b * 8 + c) * SIG_N;
        lsig[c * 592 + tid] = sb[tid];
        if (tid < 72) lsig[c * 592 + 512 + tid] = sb[512 + tid];
    }
    __syncthreads();

    // init A = chunk 0
    float s1A = lsig[i];
    float s2A = lsig[8 + i * 8 + j];
    float s3A = lsig[72 + (i * 8 + j) * 8 + k];
    float s4A[8] = { g0[0].x, g0[0].y, g0[0].z, g0[0].w,
                     g1[0].x, g1[0].y, g1[0].z, g1[0].w };

    #pragma unroll
    for (int c = 1; c < 8; ++c) {
        const float* __restrict__ lp = lsig + c * 592;
        const float4 s1r0 = *reinterpret_cast<const float4*>(lp);                       // s1B[0..3]
        const float4 s1r1 = *reinterpret_cast<const float4*>(lp + 4);                   // s1B[4..7]
        const float4 s2r0 = *reinterpret_cast<const float4*>(lp + 8 + k * 8);           // s2B[k,0..3]
        const float4 s2r1 = *reinterpret_cast<const float4*>(lp + 8 + k * 8 + 4);
        const float4 s3r0 = *reinterpret_cast<const float4*>(lp + 72 + (j * 8 + k) * 8);// s3B[j,k,0..3]
        const float4 s3r1 = *reinterpret_cast<const float4*>(lp + 72 + (j * 8 + k) * 8 + 4);
        const float s3B_ijk = lp[72 + (i * 8 + j) * 8 + k];
        const float s2B_jk  = lp[8 + j * 8 + k];
        const float s2B_ij  = lp[8 + i * 8 + j];
        const float s1B_i   = lp[i];
        const float s1B_j   = lp[j];
        const float s1B_k   = lp[k];

        // n4 (uses OLD s1A,s2A,s3A)
        s4A[0] = fmaf(s1A, s3r0.x, fmaf(s2A, s2r0.x, fmaf(s3A, s1r0.x, s4A[0] + g0[c].x)));
        s4A[1] = fmaf(s1A, s3r0.y, fmaf(s2A, s2r0.y, fmaf(s3A, s1r0.y, s4A[1] + g0[c].y)));
        s4A[2] = fmaf(s1A, s3r0.z, fmaf(s2A, s2r0.z, fmaf(s3A, s1r0.z, s4A[2] + g0[c].z)));
        s4A[3] = fmaf(s1A, s3r0.w, fmaf(s2A, s2r0.w, fmaf(s3A, s1r0.w, s4A[3] + g0[c].w)));
        s4A[4] = fmaf(s1A, s3r1.x, fmaf(s2A, s2r1.x, fmaf(s3A, s1r1.x, s4A[4] + g1[c].x)));
        s4A[5] = fmaf(s1A, s3r1.y, fmaf(s2A, s2r1.y, fmaf(s3A, s1r1.y, s4A[5] + g1[c].y)));
        s4A[6] = fmaf(s1A, s3r1.z, fmaf(s2A, s2r1.z, fmaf(s3A, s1r1.z, s4A[6] + g1[c].z)));
        s4A[7] = fmaf(s1A, s3r1.w, fmaf(s2A, s2r1.w, fmaf(s3A, s1r1.w, s4A[7] + g1[c].w)));
        // n3, n2, n1 (old values)
        const float s3n = fmaf(s1A, s2B_jk, fmaf(s2A, s1B_k, s3A + s3B_ijk));
        const float s2n = fmaf(s1A, s1B_j, s2A + s2B_ij);
        const float s1n = s1A + s1B_i;
        s3A = s3n; s2A = s2n; s1A = s1n;
    }

    // final output
    float* __restrict__ ob = out + (size_t)b * SIG_N;
    if (lane == 0) ob[i] = s1A;
    if (k == 0)    ob[8 + i * 8 + j] = s2A;
    ob[72 + (i * 8 + j) * 8 + k] = s3A;
    float4* o4 = reinterpret_cast<float4*>(ob + 584 + (size_t)row);
    o4[0] = make_float4(s4A[0], s4A[1], s4A[2], s4A[3]);
    o4[1] = make_float4(s4A[4], s4A[5], s4A[6], s4A[7]);
}

extern "C" void kernel_launch(void* const* d_in, const int* in_sizes, int n_in,
                              void* d_out, int out_size, void* d_ws, size_t ws_size,
                              hipStream_t stream)
{
    const float* inp = (const float*)d_in[0];
    const float* w1  = (const float*)d_in[1];
    const float* b1  = (const float*)d_in[2];
    const float* w2  = (const float*)d_in[3];
    const float* b2  = (const float*)d_in[4];
    const float* w3  = (const float*)d_in[5];
    const float* b3  = (const float*)d_in[6];
    float* out = (float*)d_out;
    float* ws  = (float*)d_ws;   // 64*8*4680*4 = 9.6 MB used

    chunk_sig_kernel<<<512, 512, 0, stream>>>(inp, w1, b1, w2, b2, w3, b3, ws);
    fold_kernel<<<64, 512, 0, stream>>>(ws, out);
}

// Round 6
// 91.788 us; speedup vs baseline: 1.4649x; 1.4649x over previous
//
#include <hip/hip_runtime.h>

// B=64, L=256, C_IN=5, KERNEL=4, C=8. S=253 real steps padded to 256.
// Chen-chunked: 8 chunks x 32 steps. Kernel 1: 512 blocks (b,c) x 256 thr
// (4 waves; each wave owns TWO i values: wave and wave+4). Kernel 2 folds
// the 8 chunk signatures with the Chen identity (exact).
// R5 lesson: no template switch / no 8-way inlining -> no spills.
#define L_IN    256
#define S_STEPS 253
#define CIN     5
#define CH_LEN  32
#define SIG_N   4680   // 8 + 64 + 512 + 4096

// ---- conv-augment one path row r (0..252) -> 8 floats -------------------
__device__ __forceinline__ void path_row(
    const float* __restrict__ x, int r,
    const float* __restrict__ w1, const float* __restrict__ b1,
    const float* __restrict__ w2, const float* __restrict__ b2,
    const float* __restrict__ w3, const float* __restrict__ b3,
    float o[8])
{
    float h1[8];
    #pragma unroll
    for (int q = 0; q < 8; ++q) h1[q] = b1[q];
    #pragma unroll
    for (int kk = 0; kk < 4; ++kk) {
        #pragma unroll
        for (int ci = 0; ci < CIN; ++ci) {
            float v = x[(r + kk) * CIN + ci];
            #pragma unroll
            for (int q = 0; q < 8; ++q) h1[q] = fmaf(v, w1[q * 20 + ci * 4 + kk], h1[q]);
        }
    }
    float r1v[8];
    #pragma unroll
    for (int q = 0; q < 8; ++q) r1v[q] = h1[q] > 0.f ? h1[q] : 0.f;
    float h2[8];
    #pragma unroll
    for (int q = 0; q < 8; ++q) h2[q] = b2[q];
    #pragma unroll
    for (int p = 0; p < 8; ++p) {
        #pragma unroll
        for (int q = 0; q < 8; ++q) h2[q] = fmaf(r1v[p], w2[q * 8 + p], h2[q]);
    }
    float r2v[8];
    #pragma unroll
    for (int q = 0; q < 8; ++q) r2v[q] = h2[q] > 0.f ? h2[q] : 0.f;
    float h30 = b3[0], h31 = b3[1];
    #pragma unroll
    for (int p = 0; p < 8; ++p) {
        h30 = fmaf(r2v[p], w3[p], h30);
        h31 = fmaf(r2v[p], w3[8 + p], h31);
    }
    #pragma unroll
    for (int cc = 0; cc < 5; ++cc) o[cc] = x[(r + 3) * CIN + cc];
    o[5] = (float)(r + 3) * (1.0f / 255.0f);
    o[6] = h30;
    o[7] = h31;
}

// ---- kernel 1: per-(batch, chunk) conv + 32-step scan, 2 i's per wave ----
__global__ __launch_bounds__(256) void chunk_sig_kernel(
    const float* __restrict__ inp,
    const float* __restrict__ w1, const float* __restrict__ b1,
    const float* __restrict__ w2, const float* __restrict__ b2,
    const float* __restrict__ w3, const float* __restrict__ b3,
    float* __restrict__ ws)
{
    const int blk = blockIdx.x;     // 0..511
    const int b   = blk >> 3;       // batch
    const int c   = blk & 7;        // chunk
    const int tid = threadIdx.x;    // 0..255

    __shared__ __align__(16) float pbuf[33][8];   // path rows 32c-1 .. 32c+31
    __shared__ __align__(16) float dxs[40][8];    // 32 steps + 8 zero slop

    const float* __restrict__ x = inp + b * (L_IN * CIN);

    if (tid < 33) {
        const int r = CH_LEN * c - 1 + tid;       // global path row
        if (r >= 0 && r <= 252) {
            float o[8];
            path_row(x, r, w1, b1, w2, b2, w3, b3, o);
            #pragma unroll
            for (int ch = 0; ch < 8; ++ch) pbuf[tid][ch] = o[ch];
        } else {
            #pragma unroll
            for (int ch = 0; ch < 8; ++ch) pbuf[tid][ch] = 0.f;
        }
    }
    if (tid >= 64 && tid < 128) {                 // zero slop rows 32..39
        dxs[32 + ((tid - 64) >> 3)][tid & 7] = 0.f;
    }
    __syncthreads();
    if (tid < CH_LEN) {
        const int tg = CH_LEN * c + tid;          // global step index
        if (tg <= 252) {
            #pragma unroll
            for (int ch = 0; ch < 8; ++ch)
                dxs[tid][ch] = pbuf[tid + 1][ch] - pbuf[tid][ch];
        } else {
            #pragma unroll
            for (int ch = 0; ch < 8; ++ch) dxs[tid][ch] = 0.f;   // identity pad
        }
    }
    __syncthreads();

    // ---------------- 32-step scan ----------------
    const int wave = tid >> 6;      // i0 = wave, i1 = wave + 4 (wave-uniform)
    const int lane = tid & 63;
    const int j    = lane >> 3;
    const int k    = lane & 7;
    const int i0   = wave;

    float s1A = 0.f, s2A = 0.f, s3A = 0.f;
    float s1B = 0.f, s2B = 0.f, s3B = 0.f;
    float s4A[8], s4B[8];
    #pragma unroll
    for (int l = 0; l < 8; ++l) { s4A[l] = 0.f; s4B[l] = 0.f; }

    const float4* __restrict__ dx4 = reinterpret_cast<const float4*>(&dxs[0][0]);

    // depth-2 register pipeline over LDS reads
    float own_p[2], bb_p[2];
    float4 r0_p[2], r1_p[2];
    #pragma unroll
    for (int u = 0; u < 2; ++u) {
        own_p[u] = dxs[u][k];
        bb_p[u]  = dxs[u][j];
        r0_p[u]  = dx4[2 * u];
        r1_p[u]  = dx4[2 * u + 1];
    }

    for (int tb = 0; tb < CH_LEN; tb += 2) {
        #pragma unroll
        for (int u = 0; u < 2; ++u) {
            const int tn = tb + u + 2;            // <= 33, zeroed slop
            float  own_n = dxs[tn][k];
            float  bb_n  = dxs[tn][j];
            float4 r0_n  = dx4[2 * tn];
            float4 r1_n  = dx4[2 * tn + 1];

            const float own = own_p[u];           // dx[k] == cc
            const float bb  = bb_p[u];            // dx[j]
            const float4 r0 = r0_p[u];            // dx[0..3]
            const float4 r1 = r1_p[u];            // dx[4..7]
            // a for i0 (low half-row) and i1 = i0+4 (same component, high half)
            const float a0 = (i0 == 0) ? r0.x : (i0 == 1) ? r0.y
                           : (i0 == 2) ? r0.z : r0.w;
            const float a1 = (i0 == 0) ? r1.x : (i0 == 1) ? r1.y
                           : (i0 == 2) ? r1.z : r1.w;

            // --- update A (index i0) ---
            {
                const float t2    = fmaf(a0, 0.5f, s1A);
                const float t3    = fmaf(s1A, 0.5f, a0 * (1.0f / 6.0f));
                const float t4    = fmaf(s1A, (1.0f / 6.0f), a0 * (1.0f / 24.0f));
                const float coef3 = fmaf(bb, t3, s2A);
                const float uu    = fmaf(bb, t4, 0.5f * s2A);
                const float coef4 = fmaf(own, uu, s3A);
                s4A[0] = fmaf(coef4, r0.x, s4A[0]);
                s4A[1] = fmaf(coef4, r0.y, s4A[1]);
                s4A[2] = fmaf(coef4, r0.z, s4A[2]);
                s4A[3] = fmaf(coef4, r0.w, s4A[3]);
                s4A[4] = fmaf(coef4, r1.x, s4A[4]);
                s4A[5] = fmaf(coef4, r1.y, s4A[5]);
                s4A[6] = fmaf(coef4, r1.z, s4A[6]);
                s4A[7] = fmaf(coef4, r1.w, s4A[7]);
                s3A = fmaf(coef3, own, s3A);
                s2A = fmaf(t2, bb, s2A);
                s1A += a0;
            }
            // --- update B (index i1 = i0+4) ---
            {
                const float t2    = fmaf(a1, 0.5f, s1B);
                const float t3    = fmaf(s1B, 0.5f, a1 * (1.0f / 6.0f));
                const float t4    = fmaf(s1B, (1.0f / 6.0f), a1 * (1.0f / 24.0f));
                const float coef3 = fmaf(bb, t3, s2B);
                const float uu    = fmaf(bb, t4, 0.5f * s2B);
                const float coef4 = fmaf(own, uu, s3B);
                s4B[0] = fmaf(coef4, r0.x, s4B[0]);
                s4B[1] = fmaf(coef4, r0.y, s4B[1]);
                s4B[2] = fmaf(coef4, r0.z, s4B[2]);
                s4B[3] = fmaf(coef4, r0.w, s4B[3]);
                s4B[4] = fmaf(coef4, r1.x, s4B[4]);
                s4B[5] = fmaf(coef4, r1.y, s4B[5]);
                s4B[6] = fmaf(coef4, r1.z, s4B[6]);
                s4B[7] = fmaf(coef4, r1.w, s4B[7]);
                s3B = fmaf(coef3, own, s3B);
                s2B = fmaf(t2, bb, s2B);
                s1B += a1;
            }

            own_p[u] = own_n; bb_p[u] = bb_n;
            r0_p[u] = r0_n;   r1_p[u] = r1_n;
        }
    }

    // ---------------- epilogue: write both i-slices ----------------
    float* __restrict__ wsig = ws + (size_t)(b * 8 + c) * SIG_N;
    const int i1 = i0 + 4;
    if (lane == 0) { wsig[i0] = s1A; wsig[i1] = s1B; }
    if (k == 0) {
        wsig[8 + i0 * 8 + j] = s2A;
        wsig[8 + i1 * 8 + j] = s2B;
    }
    wsig[72 + (i0 * 8 + j) * 8 + k] = s3A;
    wsig[72 + (i1 * 8 + j) * 8 + k] = s3B;
    float4* oA = reinterpret_cast<float4*>(wsig + 584 + (size_t)((i0 * 8 + j) * 8 + k) * 8);
    oA[0] = make_float4(s4A[0], s4A[1], s4A[2], s4A[3]);
    oA[1] = make_float4(s4A[4], s4A[5], s4A[6], s4A[7]);
    float4* oB = reinterpret_cast<float4*>(wsig + 584 + (size_t)((i1 * 8 + j) * 8 + k) * 8);
    oB[0] = make_float4(s4B[0], s4B[1], s4B[2], s4B[3]);
    oB[1] = make_float4(s4B[4], s4B[5], s4B[6], s4B[7]);
}

// ---- kernel 2: left-fold 8 chunk sigs per batch via Chen identity --------
// n1 = s1A+s1B; n2 += s1A_i*s1B_j; n3 += s1A_i*s2B[jk] + s2A[ij]*s1B_k;
// n4 += s1A_i*s3B[jkl] + s2A[ij]*s2B[kl] + s3A[ijk]*s1B_l.
__global__ __launch_bounds__(512) void fold_kernel(
    const float* __restrict__ ws, float* __restrict__ out)
{
    const int b    = blockIdx.x;    // 0..63
    const int tid  = threadIdx.x;
    const int i    = tid >> 6;      // wave-uniform
    const int lane = tid & 63;
    const int j    = lane >> 3;
    const int k    = lane & 7;
    const int row  = ((i * 8 + j) * 8 + k) * 8;

    __shared__ __align__(16) float lsig[8 * 592];   // s1|s2|s3 of 8 chunks

    // preload all 8 chunks' s4 rows (global, coalesced)
    float4 g0[8], g1[8];
    #pragma unroll
    for (int c = 0; c < 8; ++c) {
        const float* p4 = ws + (size_t)(b * 8 + c) * SIG_N + 584 + row;
        g0[c] = *reinterpret_cast<const float4*>(p4);
        g1[c] = *reinterpret_cast<const float4*>(p4 + 4);
    }
    // stage s1/s2/s3 of all 8 chunks into LDS (coalesced)
    #pragma unroll
    for (int c = 0; c < 8; ++c) {
        const float* sb = ws + (size_t)(b * 8 + c) * SIG_N;
        lsig[c * 592 + tid] = sb[tid];
        if (tid < 72) lsig[c * 592 + 512 + tid] = sb[512 + tid];
    }
    __syncthreads();

    float s1A = lsig[i];
    float s2A = lsig[8 + i * 8 + j];
    float s3A = lsig[72 + (i * 8 + j) * 8 + k];
    float s4A[8] = { g0[0].x, g0[0].y, g0[0].z, g0[0].w,
                     g1[0].x, g1[0].y, g1[0].z, g1[0].w };

    #pragma unroll
    for (int c = 1; c < 8; ++c) {
        const float* __restrict__ lp = lsig + c * 592;
        const float4 s1r0 = *reinterpret_cast<const float4*>(lp);
        const float4 s1r1 = *reinterpret_cast<const float4*>(lp + 4);
        const float4 s2r0 = *reinterpret_cast<const float4*>(lp + 8 + k * 8);
        const float4 s2r1 = *reinterpret_cast<const float4*>(lp + 8 + k * 8 + 4);
        const float4 s3r0 = *reinterpret_cast<const float4*>(lp + 72 + (j * 8 + k) * 8);
        const float4 s3r1 = *reinterpret_cast<const float4*>(lp + 72 + (j * 8 + k) * 8 + 4);
        const float s3B_ijk = lp[72 + (i * 8 + j) * 8 + k];
        const float s2B_jk  = lp[8 + j * 8 + k];
        const float s2B_ij  = lp[8 + i * 8 + j];
        const float s1B_i   = lp[i];
        const float s1B_j   = lp[j];
        const float s1B_k   = lp[k];

        s4A[0] = fmaf(s1A, s3r0.x, fmaf(s2A, s2r0.x, fmaf(s3A, s1r0.x, s4A[0] + g0[c].x)));
        s4A[1] = fmaf(s1A, s3r0.y, fmaf(s2A, s2r0.y, fmaf(s3A, s1r0.y, s4A[1] + g0[c].y)));
        s4A[2] = fmaf(s1A, s3r0.z, fmaf(s2A, s2r0.z, fmaf(s3A, s1r0.z, s4A[2] + g0[c].z)));
        s4A[3] = fmaf(s1A, s3r0.w, fmaf(s2A, s2r0.w, fmaf(s3A, s1r0.w, s4A[3] + g0[c].w)));
        s4A[4] = fmaf(s1A, s3r1.x, fmaf(s2A, s2r1.x, fmaf(s3A, s1r1.x, s4A[4] + g1[c].x)));
        s4A[5] = fmaf(s1A, s3r1.y, fmaf(s2A, s2r1.y, fmaf(s3A, s1r1.y, s4A[5] + g1[c].y)));
        s4A[6] = fmaf(s1A, s3r1.z, fmaf(s2A, s2r1.z, fmaf(s3A, s1r1.z, s4A[6] + g1[c].z)));
        s4A[7] = fmaf(s1A, s3r1.w, fmaf(s2A, s2r1.w, fmaf(s3A, s1r1.w, s4A[7] + g1[c].w)));
        const float s3n = fmaf(s1A, s2B_jk, fmaf(s2A, s1B_k, s3A + s3B_ijk));
        const float s2n = fmaf(s1A, s1B_j, s2A + s2B_ij);
        const float s1n = s1A + s1B_i;
        s3A = s3n; s2A = s2n; s1A = s1n;
    }

    float* __restrict__ ob = out + (size_t)b * SIG_N;
    if (lane == 0) ob[i] = s1A;
    if (k == 0)    ob[8 + i * 8 + j] = s2A;
    ob[72 + (i * 8 + j) * 8 + k] = s3A;
    float4* o4 = reinterpret_cast<float4*>(ob + 584 + (size_t)row);
    o4[0] = make_float4(s4A[0], s4A[1], s4A[2], s4A[3]);
    o4[1] = make_float4(s4A[4], s4A[5], s4A[6], s4A[7]);
}

extern "C" void kernel_launch(void* const* d_in, const int* in_sizes, int n_in,
                              void* d_out, int out_size, void* d_ws, size_t ws_size,
                              hipStream_t stream)
{
    const float* inp = (const float*)d_in[0];
    const float* w1  = (const float*)d_in[1];
    const float* b1  = (const float*)d_in[2];
    const float* w2  = (const float*)d_in[3];
    const float* b2  = (const float*)d_in[4];
    const float* w3  = (const float*)d_in[5];
    const float* b3  = (const float*)d_in[6];
    float* out = (float*)d_out;
    float* ws  = (float*)d_ws;   // 64*8*4680*4 = 9.6 MB used

    chunk_sig_kernel<<<512, 256, 0, stream>>>(inp, w1, b1, w2, b2, w3, b3, ws);
    fold_kernel<<<64, 512, 0, stream>>>(ws, out);
}

// Round 7
// 83.873 us; speedup vs baseline: 1.6032x; 1.0944x over previous
//
#include <hip/hip_runtime.h>

// B=64, L=256, C_IN=5, KERNEL=4, C=8. 253 steps padded to 256 = 8 chunks x 32.
// ONE kernel, grid 256 = (batch 64) x (i-pair 4), block 256 thr = 4 waves,
// 1 wave/SIMD device-wide. Wave w scans chunks {w, w+4}: full level1-3 chunk
// sigs (all 8 i) -> LDS table; level-4 rows only for the block's two i's
// (i0=2iq, i1=2iq+1) in registers. Chen fold needs only level<=3 prefixes
// (small), so everything stays on-chip (R5/R6 lesson: HBM round-trips lose).
#define L_IN  256
#define CIN   5
#define SIG_N 4680   // 8 + 64 + 512 + 4096

__global__ __launch_bounds__(256, 1) void sig_fused_kernel(
    const float* __restrict__ inp,
    const float* __restrict__ w1, const float* __restrict__ b1,
    const float* __restrict__ w2, const float* __restrict__ b2,
    const float* __restrict__ w3, const float* __restrict__ b3,
    float* __restrict__ out)
{
    const int blk  = blockIdx.x;      // 0..255
    const int b    = blk >> 2;        // batch
    const int iq   = blk & 3;         // i-pair: i0=2iq, i1=2iq+1
    const int tid  = threadIdx.x;     // 0..255
    const int w    = tid >> 6;        // wave 0..3 -> chunks {w, w+4}
    const int lane = tid & 63;
    const int j    = lane >> 3;
    const int k    = lane & 7;

    __shared__ __align__(16) float dxs[264][8];    // 256 steps + zero slop
    __shared__ __align__(16) float sig3[8][600];   // per-chunk s1|s2|s3 (584 used)
    __shared__ float acc[1024];                    // s4 accum, l-major: [l][m][jk]

    // ---------------- phase 1: conv augment -> increments in dxs ----------
    const float* __restrict__ x = inp + b * (L_IN * CIN);
    float o[8];
    if (tid < 253) {
        float h1[8];
        #pragma unroll
        for (int q = 0; q < 8; ++q) h1[q] = b1[q];
        #pragma unroll
        for (int kk = 0; kk < 4; ++kk) {
            #pragma unroll
            for (int ci = 0; ci < CIN; ++ci) {
                float v = x[(tid + kk) * CIN + ci];
                #pragma unroll
                for (int q = 0; q < 8; ++q) h1[q] = fmaf(v, w1[q * 20 + ci * 4 + kk], h1[q]);
            }
        }
        float r1v[8];
        #pragma unroll
        for (int q = 0; q < 8; ++q) r1v[q] = h1[q] > 0.f ? h1[q] : 0.f;
        float h2[8];
        #pragma unroll
        for (int q = 0; q < 8; ++q) h2[q] = b2[q];
        #pragma unroll
        for (int p = 0; p < 8; ++p) {
            #pragma unroll
            for (int q = 0; q < 8; ++q) h2[q] = fmaf(r1v[p], w2[q * 8 + p], h2[q]);
        }
        float r2v[8];
        #pragma unroll
        for (int q = 0; q < 8; ++q) r2v[q] = h2[q] > 0.f ? h2[q] : 0.f;
        float h30 = b3[0], h31 = b3[1];
        #pragma unroll
        for (int p = 0; p < 8; ++p) {
            h30 = fmaf(r2v[p], w3[p], h30);
            h31 = fmaf(r2v[p], w3[8 + p], h31);
        }
        #pragma unroll
        for (int cc = 0; cc < 5; ++cc) o[cc] = x[(tid + 3) * CIN + cc];
        o[5] = (float)(tid + 3) * (1.0f / 255.0f);
        o[6] = h30;
        o[7] = h31;
    }
    if (tid < 88) dxs[253 + (tid >> 3)][tid & 7] = 0.f;  // zero pad rows 253..263
    #pragma unroll
    for (int z = 0; z < 4; ++z) acc[tid * 4 + z] = 0.f;
    if (tid < 253) {
        #pragma unroll
        for (int ch = 0; ch < 8; ++ch) dxs[tid][ch] = o[ch];   // path rows
    }
    __syncthreads();
    float prevr[8];
    if (tid < 253) {
        #pragma unroll
        for (int ch = 0; ch < 8; ++ch) prevr[ch] = (tid > 0) ? dxs[tid - 1][ch] : 0.f;
    }
    __syncthreads();
    if (tid < 253) {
        #pragma unroll
        for (int ch = 0; ch < 8; ++ch) dxs[tid][ch] = o[ch] - prevr[ch];  // increments
    }
    __syncthreads();

    // ---------------- phase 2: chunk scans ----------------
    const float4* __restrict__ dx4 = reinterpret_cast<const float4*>(&dxs[0][0]);
    float s4v[2][2][8];   // [half][m][l], level-4 rows for the block's 2 i's
    #pragma unroll
    for (int hh = 0; hh < 2; ++hh)
        #pragma unroll
        for (int m = 0; m < 2; ++m)
            #pragma unroll
            for (int l = 0; l < 8; ++l) s4v[hh][m][l] = 0.f;

    #pragma unroll
    for (int half = 0; half < 2; ++half) {
        const int cc2   = w + 4 * half;   // chunk id (wave-uniform)
        const int rbase = cc2 * 32;

        float t1[8], t2s[8], t3s[8];      // full level1-3 state, all 8 i
        #pragma unroll
        for (int i = 0; i < 8; ++i) { t1[i] = 0.f; t2s[i] = 0.f; t3s[i] = 0.f; }
        float u1[2] = {0.f, 0.f}, u2[2] = {0.f, 0.f}, u3[2] = {0.f, 0.f};  // copies for i0,i1

        // depth-2 pipeline over LDS
        float own_p[2], bb_p[2];
        float4 r0_p[2], r1_p[2];
        #pragma unroll
        for (int u = 0; u < 2; ++u) {
            own_p[u] = dxs[rbase + u][k];
            bb_p[u]  = dxs[rbase + u][j];
            r0_p[u]  = dx4[2 * (rbase + u)];
            r1_p[u]  = dx4[2 * (rbase + u) + 1];
        }

        for (int tb = 0; tb < 32; tb += 2) {
            #pragma unroll
            for (int u = 0; u < 2; ++u) {
                const int tn = rbase + tb + u + 2;   // <= 257, zeroed slop
                float  own_n = dxs[tn][k];
                float  bb_n  = dxs[tn][j];
                float4 r0_n  = dx4[2 * tn];
                float4 r1_n  = dx4[2 * tn + 1];

                const float own = own_p[u];   // dx[k]
                const float bb  = bb_p[u];    // dx[j]
                const float4 r0 = r0_p[u];    // dx[0..3]
                const float4 r1 = r1_p[u];    // dx[4..7]
                const float rr[8] = { r0.x, r0.y, r0.z, r0.w, r1.x, r1.y, r1.z, r1.w };
                // block's two a values (block-uniform iq select)
                const float a0 = (iq == 0) ? r0.x : (iq == 1) ? r0.z
                               : (iq == 2) ? r1.x : r1.z;
                const float a1 = (iq == 0) ? r0.y : (iq == 1) ? r0.w
                               : (iq == 2) ? r1.y : r1.w;

                // level-4 coefs from OLD u-state
                float c4_0, c4_1;
                {
                    const float t4 = fmaf(u1[0], (1.0f / 6.0f), a0 * (1.0f / 24.0f));
                    const float uu = fmaf(bb, t4, 0.5f * u2[0]);
                    c4_0 = fmaf(own, uu, u3[0]);
                }
                {
                    const float t4 = fmaf(u1[1], (1.0f / 6.0f), a1 * (1.0f / 24.0f));
                    const float uu = fmaf(bb, t4, 0.5f * u2[1]);
                    c4_1 = fmaf(own, uu, u3[1]);
                }
                #pragma unroll
                for (int l = 0; l < 8; ++l) {
                    s4v[half][0][l] = fmaf(c4_0, rr[l], s4v[half][0][l]);
                    s4v[half][1][l] = fmaf(c4_1, rr[l], s4v[half][1][l]);
                }
                // update u copies (i0, i1)
                {
                    const float c3 = fmaf(bb, fmaf(u1[0], 0.5f, a0 * (1.0f / 6.0f)), u2[0]);
                    u3[0] = fmaf(c3, own, u3[0]);
                    u2[0] = fmaf(fmaf(a0, 0.5f, u1[0]), bb, u2[0]);
                    u1[0] += a0;
                }
                {
                    const float c3 = fmaf(bb, fmaf(u1[1], 0.5f, a1 * (1.0f / 6.0f)), u2[1]);
                    u3[1] = fmaf(c3, own, u3[1]);
                    u2[1] = fmaf(fmaf(a1, 0.5f, u1[1]), bb, u2[1]);
                    u1[1] += a1;
                }
                // full level1-3 update, all 8 i
                #pragma unroll
                for (int i = 0; i < 8; ++i) {
                    const float a  = rr[i];
                    const float c3 = fmaf(bb, fmaf(t1[i], 0.5f, a * (1.0f / 6.0f)), t2s[i]);
                    t3s[i] = fmaf(c3, own, t3s[i]);
                    t2s[i] = fmaf(fmaf(a, 0.5f, t1[i]), bb, t2s[i]);
                    t1[i] += a;
                }

                own_p[u] = own_n; bb_p[u] = bb_n;
                r0_p[u] = r0_n;   r1_p[u] = r1_n;
            }
        }

        // dump chunk level1-3 into the table
        if (lane == 0) {
            #pragma unroll
            for (int i = 0; i < 8; ++i) sig3[cc2][i] = t1[i];
        }
        if (k == 0) {
            #pragma unroll
            for (int i = 0; i < 8; ++i) sig3[cc2][8 + i * 8 + j] = t2s[i];
        }
        #pragma unroll
        for (int i = 0; i < 8; ++i) sig3[cc2][72 + (i * 8 + j) * 8 + k] = t3s[i];
    }
    __syncthreads();   // all 8 chunks' sig3 visible

    // ---------------- phase 3: Chen prefixes + level-4 contributions ------
    const int i0 = 2 * iq;
    const int i1 = 2 * iq + 1;
    float p1[2] = {0.f, 0.f}, p2[2] = {0.f, 0.f}, p3[2] = {0.f, 0.f};

    auto combine = [&](int cc) {
        const float* __restrict__ lp = sig3[cc];
        const float s1j  = lp[j];
        const float s1k  = lp[k];
        const float s2jk = lp[8 + j * 8 + k];
        #pragma unroll
        for (int m = 0; m < 2; ++m) {
            const int i = i0 + m;
            const float s1i  = lp[i];
            const float s2ij = lp[8 + i * 8 + j];
            const float s3i  = lp[72 + (i * 8 + j) * 8 + k];
            const float np3 = p3[m] + s3i + p1[m] * s2jk + p2[m] * s1k;  // old p1,p2
            const float np2 = p2[m] + s2ij + p1[m] * s1j;                // old p1
            p3[m] = np3; p2[m] = np2; p1[m] += s1i;
        }
    };
    auto contrib = [&](int cc, int half) {
        const float* __restrict__ lp = sig3[cc];
        const float4 s1a = *reinterpret_cast<const float4*>(lp);
        const float4 s1b = *reinterpret_cast<const float4*>(lp + 4);
        const float4 s2a = *reinterpret_cast<const float4*>(lp + 8 + k * 8);
        const float4 s2b = *reinterpret_cast<const float4*>(lp + 8 + k * 8 + 4);
        const float4 s3a = *reinterpret_cast<const float4*>(lp + 72 + (j * 8 + k) * 8);
        const float4 s3b = *reinterpret_cast<const float4*>(lp + 72 + (j * 8 + k) * 8 + 4);
        const float s1r[8] = { s1a.x, s1a.y, s1a.z, s1a.w, s1b.x, s1b.y, s1b.z, s1b.w };
        const float s2r[8] = { s2a.x, s2a.y, s2a.z, s2a.w, s2b.x, s2b.y, s2b.z, s2b.w };
        const float s3r[8] = { s3a.x, s3a.y, s3a.z, s3a.w, s3b.x, s3b.y, s3b.z, s3b.w };
        #pragma unroll
        for (int m = 0; m < 2; ++m) {
            #pragma unroll
            for (int l = 0; l < 8; ++l) {
                s4v[half][m][l] = fmaf(p1[m], s3r[l],
                                   fmaf(p2[m], s2r[l],
                                    fmaf(p3[m], s1r[l], s4v[half][m][l])));
            }
        }
    };

    for (int cc = 0; cc < w; ++cc) combine(cc);        // P before chunk w
    contrib(w, 0);
    for (int cc = w; cc < w + 4; ++cc) combine(cc);    // P before chunk w+4
    contrib(w + 4, 1);

    float* __restrict__ ob = out + (size_t)b * SIG_N;
    if (w == 3) {
        combine(7);                                    // final levels 1..3
        #pragma unroll
        for (int m = 0; m < 2; ++m) {
            const int i = i0 + m;
            if (lane == 0) ob[i] = p1[m];
            if (k == 0)    ob[8 + i * 8 + j] = p2[m];
            ob[72 + (i * 8 + j) * 8 + k] = p3[m];
        }
    }

    // ---------------- phase 4: accumulate s4 contributions ----------------
    // acc layout l-major: acc[l*128 + m*64 + lane] -> stride-1 per wave access
    #pragma unroll
    for (int ph = 0; ph < 4; ++ph) {
        if (w == ph) {
            #pragma unroll
            for (int m = 0; m < 2; ++m)
                #pragma unroll
                for (int l = 0; l < 8; ++l)
                    acc[l * 128 + m * 64 + lane] += s4v[0][m][l] + s4v[1][m][l];
        }
        __syncthreads();
    }

    // ---------------- phase 5: write s4 (1024 floats per block) -----------
    {
        const int m2 = tid >> 7;
        const int jk = (tid >> 1) & 63;
        const int lb = (tid & 1) * 4;
        float4 v;
        v.x = acc[(lb + 0) * 128 + m2 * 64 + jk];
        v.y = acc[(lb + 1) * 128 + m2 * 64 + jk];
        v.z = acc[(lb + 2) * 128 + m2 * 64 + jk];
        v.w = acc[(lb + 3) * 128 + m2 * 64 + jk];
        *reinterpret_cast<float4*>(ob + 584 + iq * 1024 + tid * 4) = v;
    }
}

extern "C" void kernel_launch(void* const* d_in, const int* in_sizes, int n_in,
                              void* d_out, int out_size, void* d_ws, size_t ws_size,
                              hipStream_t stream)
{
    const float* inp = (const float*)d_in[0];
    const float* w1  = (const float*)d_in[1];
    const float* b1  = (const float*)d_in[2];
    const float* w2  = (const float*)d_in[3];
    const float* b2  = (const float*)d_in[4];
    const float* w3  = (const float*)d_in[5];
    const float* b3  = (const float*)d_in[6];
    float* out = (float*)d_out;

    sig_fused_kernel<<<256, 256, 0, stream>>>(inp, w1, b1, w2, b2, w3, b3, out);
}

// Round 8
// 81.354 us; speedup vs baseline: 1.6528x; 1.0310x over previous
//
#include <hip/hip_runtime.h>

// B=64, L=256, C_IN=5, KERNEL=4, C=8. 253 steps padded to 256 = 8 chunks x 32.
// ONE kernel, 256 blocks = (batch 64) x (i-pair 4), 512 thr = 8 waves.
// wave = chunk (32 serial iters, R7 had 64) and 2 waves/SIMD device-wide
// (R7 had 1 -> ~30% issue efficiency; TLP is the lever this round).
// Wave scans its chunk tracking FULL levels 1-3 (all 8 i, for the Chen table)
// + level-4 rows for the block's two i's. Chen fold is all in-LDS.
#define L_IN  256
#define CIN   5
#define SIG_N 4680   // 8 + 64 + 512 + 4096

__global__ __launch_bounds__(512) void sig_fused_kernel(
    const float* __restrict__ inp,
    const float* __restrict__ w1, const float* __restrict__ b1,
    const float* __restrict__ w2, const float* __restrict__ b2,
    const float* __restrict__ w3, const float* __restrict__ b3,
    float* __restrict__ out)
{
    const int blk  = blockIdx.x;      // 0..255
    const int b    = blk >> 2;        // batch
    const int iq   = blk & 3;         // i0=2iq, i1=2iq+1
    const int tid  = threadIdx.x;     // 0..511
    const int w    = tid >> 6;        // wave 0..7 = chunk id
    const int lane = tid & 63;
    const int j    = lane >> 3;
    const int k    = lane & 7;

    __shared__ __align__(16) float dxs[264][8];    // 256 steps + zero slop
    __shared__ __align__(16) float sig3[8][592];   // per-chunk s1|s2|s3 (584 used)
    __shared__ __align__(16) float acc[1024];      // s4 accum [m][jk][l]
    __shared__ float pad_lds[8192];                // occupancy cap: <=2 blocks/CU

    // keep pad_lds allocated (never executes; grid size opaque to compiler)
    if (blk & 0x40000000) out[0] = pad_lds[tid];

    // ---------------- phase 1: conv augment -> increments ----------------
    const float* __restrict__ x = inp + b * (L_IN * CIN);
    float o[8];
    if (tid < 253) {
        float h1[8];
        #pragma unroll
        for (int q = 0; q < 8; ++q) h1[q] = b1[q];
        #pragma unroll
        for (int kk = 0; kk < 4; ++kk) {
            #pragma unroll
            for (int ci = 0; ci < CIN; ++ci) {
                float v = x[(tid + kk) * CIN + ci];
                #pragma unroll
                for (int q = 0; q < 8; ++q) h1[q] = fmaf(v, w1[q * 20 + ci * 4 + kk], h1[q]);
            }
        }
        float r1v[8];
        #pragma unroll
        for (int q = 0; q < 8; ++q) r1v[q] = h1[q] > 0.f ? h1[q] : 0.f;
        float h2[8];
        #pragma unroll
        for (int q = 0; q < 8; ++q) h2[q] = b2[q];
        #pragma unroll
        for (int p = 0; p < 8; ++p) {
            #pragma unroll
            for (int q = 0; q < 8; ++q) h2[q] = fmaf(r1v[p], w2[q * 8 + p], h2[q]);
        }
        float r2v[8];
        #pragma unroll
        for (int q = 0; q < 8; ++q) r2v[q] = h2[q] > 0.f ? h2[q] : 0.f;
        float h30 = b3[0], h31 = b3[1];
        #pragma unroll
        for (int p = 0; p < 8; ++p) {
            h30 = fmaf(r2v[p], w3[p], h30);
            h31 = fmaf(r2v[p], w3[8 + p], h31);
        }
        #pragma unroll
        for (int cc = 0; cc < 5; ++cc) o[cc] = x[(tid + 3) * CIN + cc];
        o[5] = (float)(tid + 3) * (1.0f / 255.0f);
        o[6] = h30;
        o[7] = h31;
    }
    if (tid < 88) dxs[253 + (tid >> 3)][tid & 7] = 0.f;   // zero rows 253..263
    acc[tid] = 0.f; acc[tid + 512] = 0.f;
    if (tid < 253) {
        #pragma unroll
        for (int ch = 0; ch < 8; ++ch) dxs[tid][ch] = o[ch];   // path rows
    }
    __syncthreads();
    float prevr[8];
    if (tid < 253) {
        #pragma unroll
        for (int ch = 0; ch < 8; ++ch) prevr[ch] = (tid > 0) ? dxs[tid - 1][ch] : 0.f;
    }
    __syncthreads();
    if (tid < 253) {
        #pragma unroll
        for (int ch = 0; ch < 8; ++ch) dxs[tid][ch] = o[ch] - prevr[ch];
    }
    __syncthreads();

    // ---------------- phase 2: one 32-step chunk per wave ----------------
    const int rbase = w * 32;
    float t1[8], t2r[8], t3r[8];          // full level1-3 (all 8 i) for table
    float u1[2] = {0.f, 0.f}, u2[2] = {0.f, 0.f}, u3[2] = {0.f, 0.f};
    float s4v[2][8];
    #pragma unroll
    for (int i = 0; i < 8; ++i) { t1[i] = 0.f; t2r[i] = 0.f; t3r[i] = 0.f; }
    #pragma unroll
    for (int m = 0; m < 2; ++m)
        #pragma unroll
        for (int l = 0; l < 8; ++l) s4v[m][l] = 0.f;

    const float4* __restrict__ dx4 = reinterpret_cast<const float4*>(&dxs[0][0]);
    float own_p[2], bb_p[2];
    float4 r0_p[2], r1_p[2];
    #pragma unroll
    for (int u = 0; u < 2; ++u) {
        own_p[u] = dxs[rbase + u][k];
        bb_p[u]  = dxs[rbase + u][j];
        r0_p[u]  = dx4[2 * (rbase + u)];
        r1_p[u]  = dx4[2 * (rbase + u) + 1];
    }

    for (int tb = 0; tb < 32; tb += 2) {
        #pragma unroll
        for (int u = 0; u < 2; ++u) {
            const int tn = rbase + tb + u + 2;   // <= 257, zeroed slop
            float  own_n = dxs[tn][k];
            float  bb_n  = dxs[tn][j];
            float4 r0_n  = dx4[2 * tn];
            float4 r1_n  = dx4[2 * tn + 1];

            const float own = own_p[u];   // dx[k]
            const float bb  = bb_p[u];    // dx[j]
            const float4 r0 = r0_p[u];
            const float4 r1 = r1_p[u];
            const float rr[8] = { r0.x, r0.y, r0.z, r0.w, r1.x, r1.y, r1.z, r1.w };
            const float a0 = (iq == 0) ? r0.x : (iq == 1) ? r0.z
                           : (iq == 2) ? r1.x : r1.z;
            const float a1 = (iq == 0) ? r0.y : (iq == 1) ? r0.w
                           : (iq == 2) ? r1.y : r1.w;

            // level-4 for the block's two i's (u-state is their private copy)
            const float c4_0 = fmaf(own, fmaf(bb, fmaf(u1[0], (1.0f / 6.0f),
                                a0 * (1.0f / 24.0f)), 0.5f * u2[0]), u3[0]);
            const float c4_1 = fmaf(own, fmaf(bb, fmaf(u1[1], (1.0f / 6.0f),
                                a1 * (1.0f / 24.0f)), 0.5f * u2[1]), u3[1]);
            #pragma unroll
            for (int l = 0; l < 8; ++l) {
                s4v[0][l] = fmaf(c4_0, rr[l], s4v[0][l]);
                s4v[1][l] = fmaf(c4_1, rr[l], s4v[1][l]);
            }
            u3[0] = fmaf(fmaf(bb, fmaf(u1[0], 0.5f, a0 * (1.0f / 6.0f)), u2[0]), own, u3[0]);
            u2[0] = fmaf(fmaf(a0, 0.5f, u1[0]), bb, u2[0]);
            u1[0] += a0;
            u3[1] = fmaf(fmaf(bb, fmaf(u1[1], 0.5f, a1 * (1.0f / 6.0f)), u2[1]), own, u3[1]);
            u2[1] = fmaf(fmaf(a1, 0.5f, u1[1]), bb, u2[1]);
            u1[1] += a1;

            // full level1-3 update for the Chen table
            #pragma unroll
            for (int i = 0; i < 8; ++i) {
                const float a  = rr[i];
                const float c3 = fmaf(bb, fmaf(t1[i], 0.5f, a * (1.0f / 6.0f)), t2r[i]);
                t3r[i] = fmaf(c3, own, t3r[i]);
                t2r[i] = fmaf(fmaf(a, 0.5f, t1[i]), bb, t2r[i]);
                t1[i] += a;
            }

            own_p[u] = own_n; bb_p[u] = bb_n;
            r0_p[u] = r0_n;   r1_p[u] = r1_n;
        }
    }

    // chunk level1-3 -> table
    if (lane == 0) {
        #pragma unroll
        for (int i = 0; i < 8; ++i) sig3[w][i] = t1[i];
    }
    if (k == 0) {
        #pragma unroll
        for (int i = 0; i < 8; ++i) sig3[w][8 + i * 8 + j] = t2r[i];
    }
    #pragma unroll
    for (int i = 0; i < 8; ++i) sig3[w][72 + (i * 8 + j) * 8 + k] = t3r[i];
    __syncthreads();

    // ---------------- phase 3: Chen prefix + level-4 contribution ---------
    const int i0 = 2 * iq;
    float p1[2] = {0.f, 0.f}, p2[2] = {0.f, 0.f}, p3[2] = {0.f, 0.f};

    auto combine = [&](int cc) {
        const float* __restrict__ lp = sig3[cc];
        const float s1j  = lp[j];
        const float s1k  = lp[k];
        const float s2jk = lp[8 + j * 8 + k];
        #pragma unroll
        for (int m = 0; m < 2; ++m) {
            const int i = i0 + m;
            const float s1i  = lp[i];
            const float s2ij = lp[8 + i * 8 + j];
            const float s3i  = lp[72 + (i * 8 + j) * 8 + k];
            const float np3 = p3[m] + s3i + p1[m] * s2jk + p2[m] * s1k;
            const float np2 = p2[m] + s2ij + p1[m] * s1j;
            p3[m] = np3; p2[m] = np2; p1[m] += s1i;
        }
    };

    for (int cc = 0; cc < w; ++cc) combine(cc);   // prefix before own chunk
    {   // s4v += P (x) own-chunk lower levels
        const float* __restrict__ lp = sig3[w];
        const float4 s1a = *reinterpret_cast<const float4*>(lp);
        const float4 s1b = *reinterpret_cast<const float4*>(lp + 4);
        const float4 s2a = *reinterpret_cast<const float4*>(lp + 8 + k * 8);
        const float4 s2b = *reinterpret_cast<const float4*>(lp + 8 + k * 8 + 4);
        const float4 s3a = *reinterpret_cast<const float4*>(lp + 72 + (j * 8 + k) * 8);
        const float4 s3b = *reinterpret_cast<const float4*>(lp + 72 + (j * 8 + k) * 8 + 4);
        const float s1r[8] = { s1a.x, s1a.y, s1a.z, s1a.w, s1b.x, s1b.y, s1b.z, s1b.w };
        const float s2r[8] = { s2a.x, s2a.y, s2a.z, s2a.w, s2b.x, s2b.y, s2b.z, s2b.w };
        const float s3r[8] = { s3a.x, s3a.y, s3a.z, s3a.w, s3b.x, s3b.y, s3b.z, s3b.w };
        #pragma unroll
        for (int m = 0; m < 2; ++m)
            #pragma unroll
            for (int l = 0; l < 8; ++l)
                s4v[m][l] = fmaf(p1[m], s3r[l],
                             fmaf(p2[m], s2r[l],
                              fmaf(p3[m], s1r[l], s4v[m][l])));
    }

    float* __restrict__ ob = out + (size_t)b * SIG_N;
    if (w == 7) {
        combine(7);   // full-path levels 1..3
        #pragma unroll
        for (int m = 0; m < 2; ++m) {
            const int i = i0 + m;
            if (lane == 0) ob[i] = p1[m];
            if (k == 0)    ob[8 + i * 8 + j] = p2[m];
            ob[72 + (i * 8 + j) * 8 + k] = p3[m];
        }
    }

    // ---------------- phase 4: accumulate s4 across the 8 waves ----------
    #pragma unroll
    for (int ph = 0; ph < 8; ++ph) {
        if (w == ph) {
            #pragma unroll
            for (int m = 0; m < 2; ++m) {
                float4* ap = reinterpret_cast<float4*>(&acc[m * 512 + lane * 8]);
                float4 v0 = ap[0], v1 = ap[1];
                v0.x += s4v[m][0]; v0.y += s4v[m][1]; v0.z += s4v[m][2]; v0.w += s4v[m][3];
                v1.x += s4v[m][4]; v1.y += s4v[m][5]; v1.z += s4v[m][6]; v1.w += s4v[m][7];
                ap[0] = v0; ap[1] = v1;
            }
        }
        __syncthreads();
    }

    // ---------------- phase 5: coalesced s4 store ------------------------
    // local index 2*tid decomposes as m*512 + (j*8+k)*8 + l  == global layout
    float2 v = *reinterpret_cast<float2*>(&acc[2 * tid]);
    *reinterpret_cast<float2*>(ob + 584 + iq * 1024 + 2 * tid) = v;
}

extern "C" void kernel_launch(void* const* d_in, const int* in_sizes, int n_in,
                              void* d_out, int out_size, void* d_ws, size_t ws_size,
                              hipStream_t stream)
{
    const float* inp = (const float*)d_in[0];
    const float* w1  = (const float*)d_in[1];
    const float* b1  = (const float*)d_in[2];
    const float* w2  = (const float*)d_in[3];
    const float* b2  = (const float*)d_in[4];
    const float* w3  = (const float*)d_in[5];
    const float* b3  = (const float*)d_in[6];
    float* out = (float*)d_out;

    sig_fused_kernel<<<256, 512, 0, stream>>>(inp, w1, b1, w2, b2, w3, b3, out);
}